// Round 3
// baseline (392.827 us; speedup 1.0000x reference)
//
#include <hip/hip_runtime.h>

// out[b,t] = sum_d x[b,t,d] * stimulus[b,t,d]
// 65536 rows x 768 fp32. One wave per 8 sequential rows, depth-2 software
// pipeline: prefetch the next row's 6 float4s while doing FMAs + reduction on
// the current row. Steady state = 12 loads (192 B/lane) in flight per wave at
// 32 waves/CU -> ~6 KB/CU outstanding, which is what Little's law needs to
// approach HBM BW at ~400-600 cy latency. Keep VGPR <= 64 for 8 waves/SIMD.

constexpr int D4   = 768 / 4;      // 192 float4 per row
constexpr int ROWS = 8 * 8192;     // 65536
constexpr int RPW  = 8;            // rows per wave (sequential, pipelined)

__global__ __launch_bounds__(256, 8) void row_dot_kernel(
    const float4* __restrict__ x,
    const float4* __restrict__ s,
    float* __restrict__ out)
{
    const int wave = (blockIdx.x * blockDim.x + threadIdx.x) >> 6;
    const int lane = threadIdx.x & 63;

    const size_t row0 = (size_t)wave * RPW;
    size_t p = row0 * D4 + lane;

    // Prologue: load row 0.
    float4 ca0 = x[p];       float4 cb0 = s[p];
    float4 ca1 = x[p + 64];  float4 cb1 = s[p + 64];
    float4 ca2 = x[p + 128]; float4 cb2 = s[p + 128];

#pragma unroll
    for (int r = 0; r < RPW; ++r) {
        float4 na0, na1, na2, nb0, nb1, nb2;
        if (r < RPW - 1) {
            const size_t q = p + D4;
            na0 = x[q];       nb0 = s[q];
            na1 = x[q + 64];  nb1 = s[q + 64];
            na2 = x[q + 128]; nb2 = s[q + 128];
        }

        float t = 0.0f;
        t = fmaf(ca0.x, cb0.x, t);
        t = fmaf(ca0.y, cb0.y, t);
        t = fmaf(ca0.z, cb0.z, t);
        t = fmaf(ca0.w, cb0.w, t);
        t = fmaf(ca1.x, cb1.x, t);
        t = fmaf(ca1.y, cb1.y, t);
        t = fmaf(ca1.z, cb1.z, t);
        t = fmaf(ca1.w, cb1.w, t);
        t = fmaf(ca2.x, cb2.x, t);
        t = fmaf(ca2.y, cb2.y, t);
        t = fmaf(ca2.z, cb2.z, t);
        t = fmaf(ca2.w, cb2.w, t);

        // 64-lane butterfly reduction (overlaps with outstanding prefetch).
#pragma unroll
        for (int off = 32; off > 0; off >>= 1)
            t += __shfl_xor(t, off, 64);

        if (lane == 0) out[row0 + r] = t;

        p += D4;
        ca0 = na0; ca1 = na1; ca2 = na2;
        cb0 = nb0; cb1 = nb1; cb2 = nb2;
    }
}

extern "C" void kernel_launch(void* const* d_in, const int* in_sizes, int n_in,
                              void* d_out, int out_size, void* d_ws, size_t ws_size,
                              hipStream_t stream)
{
    const float4* x = (const float4*)d_in[0];
    const float4* s = (const float4*)d_in[1];
    float* out = (float*)d_out;

    // 65536 rows / 8 rows-per-wave = 8192 waves; 4 waves per 256-thread block.
    const int blocks = (ROWS / RPW) / 4;   // 2048
    row_dot_kernel<<<blocks, 256, 0, stream>>>(x, s, out);
}

// Round 4
// 385.447 us; speedup vs baseline: 1.0191x; 1.0191x over previous
//
#include <hip/hip_runtime.h>

// out[b,t] = sum_d x[b,t,d] * stimulus[b,t,d]
// 65536 rows x 768 fp32. One wave per 8 rows, processed as 4 pairs with a
// depth-2 pipeline: issue ALL 12 float4 loads of pair k+1, sched_barrier(0),
// then consume pair k. Forces ~24 outstanding vector loads per wave
// (compiler's pressure heuristic collapsed this to ~2-4 in rounds 1-3,
// VGPR_Count=16/32 -> ~3 TB/s delivered, latency-bound).
// __launch_bounds__(256,4) -> 128 VGPR budget; payload needs ~110.

constexpr int D4   = 768 / 4;      // 192 float4 per row
constexpr int ROWS = 8 * 8192;     // 65536
constexpr int RPW  = 8;            // rows per wave (4 pipelined pairs)

__global__ __launch_bounds__(256, 4) void row_dot_kernel(
    const float4* __restrict__ x,
    const float4* __restrict__ s,
    float* __restrict__ out)
{
    const int wave = (blockIdx.x * blockDim.x + threadIdx.x) >> 6;
    const int lane = threadIdx.x & 63;
    const size_t row0 = (size_t)wave * RPW;

    float4 ca[6], cb[6];   // current pair: rows {0,1} -> slots {0..2},{3..5}
    float4 na[6], nb[6];   // next pair

    size_t base = row0 * D4 + lane;

    // Prologue: issue pair 0's 12 loads.
#pragma unroll
    for (int j = 0; j < 2; ++j)
#pragma unroll
        for (int c = 0; c < 3; ++c) {
            ca[j * 3 + c] = x[base + j * D4 + c * 64];
            cb[j * 3 + c] = s[base + j * D4 + c * 64];
        }
    __builtin_amdgcn_sched_barrier(0);

#pragma unroll
    for (int p = 0; p < RPW / 2; ++p) {
        // Issue next pair's 12 loads BEFORE consuming current pair.
        if (p < RPW / 2 - 1) {
            const size_t nxt = base + 2 * D4;
#pragma unroll
            for (int j = 0; j < 2; ++j)
#pragma unroll
                for (int c = 0; c < 3; ++c) {
                    na[j * 3 + c] = x[nxt + j * D4 + c * 64];
                    nb[j * 3 + c] = s[nxt + j * D4 + c * 64];
                }
        }
        __builtin_amdgcn_sched_barrier(0);

        // Consume current pair.
        float t0 = 0.0f, t1 = 0.0f;
#pragma unroll
        for (int c = 0; c < 3; ++c) {
            t0 = fmaf(ca[c].x, cb[c].x, t0);
            t0 = fmaf(ca[c].y, cb[c].y, t0);
            t0 = fmaf(ca[c].z, cb[c].z, t0);
            t0 = fmaf(ca[c].w, cb[c].w, t0);
            t1 = fmaf(ca[3 + c].x, cb[3 + c].x, t1);
            t1 = fmaf(ca[3 + c].y, cb[3 + c].y, t1);
            t1 = fmaf(ca[3 + c].z, cb[3 + c].z, t1);
            t1 = fmaf(ca[3 + c].w, cb[3 + c].w, t1);
        }

        // Two interleaved 64-lane butterfly reductions.
#pragma unroll
        for (int off = 32; off > 0; off >>= 1) {
            t0 += __shfl_xor(t0, off, 64);
            t1 += __shfl_xor(t1, off, 64);
        }

        if (lane == 0) {
            out[row0 + 2 * p]     = t0;
            out[row0 + 2 * p + 1] = t1;
        }

        base += 2 * D4;
#pragma unroll
        for (int i = 0; i < 6; ++i) {
            ca[i] = na[i]; cb[i] = nb[i];
        }
        __builtin_amdgcn_sched_barrier(0);
    }
}

extern "C" void kernel_launch(void* const* d_in, const int* in_sizes, int n_in,
                              void* d_out, int out_size, void* d_ws, size_t ws_size,
                              hipStream_t stream)
{
    const float4* x = (const float4*)d_in[0];
    const float4* s = (const float4*)d_in[1];
    float* out = (float*)d_out;

    // 65536 rows / 8 rows-per-wave = 8192 waves; 4 waves per 256-thread block.
    const int blocks = (ROWS / RPW) / 4;   // 2048
    row_dot_kernel<<<blocks, 256, 0, stream>>>(x, s, out);
}